// Round 1
// baseline (145.165 us; speedup 1.0000x reference)
//
#include <hip/hip_runtime.h>
#include <hip/hip_bf16.h>

#define T_ 4096
#define C_ 1024
#define H_ 64
#define LSTR 72    // P-buffer LDS row stride (bf16 elems)
#define XBS 1032   // x-tile LDS row stride (bf16 elems): mult-8 (16B align), 4-way banks max

typedef short bf16x8 __attribute__((ext_vector_type(8)));
typedef float f32x4 __attribute__((ext_vector_type(4)));

__device__ __forceinline__ short f2bf(float f) {
  union { __hip_bfloat16 h; short s; } u;
  u.h = __float2bfloat16(f);
  return u.s;
}
__device__ __forceinline__ unsigned pack2(float a, float b) {
  return ((unsigned)(unsigned short)f2bf(b) << 16) | (unsigned short)f2bf(a);
}

// ---- kernel 0: W[c][h] fp32 -> Wtf in MFMA B-FRAG ORDER:
// Wtf[((which*8 + c)*16 + ks*4 + nt)*512 + lane*8 + j] =
//   W_which[cc = c*128+ks*32+quad*8+j][h = nt*16+m],  lane = quad*16+m.
// Consumer loads are then base + f*512 + lane*8 : contiguous 1KB bursts.
__global__ void wtrans_kernel(const float* __restrict__ Wk,
                              const float* __restrict__ Wq,
                              const float* __restrict__ Wv,
                              __hip_bfloat16* __restrict__ Wtf) {
  int tid = blockIdx.x * 256 + threadIdx.x;  // 0..196607 exact
  const int j = tid & 7;
  const int lane = (tid >> 3) & 63;
  const int m = lane & 15;
  const int quad = lane >> 4;
  const int f = (tid >> 9) & 15;
  const int nt = f & 3;
  const int ks = f >> 2;
  const int c = (tid >> 13) & 7;
  const int which = tid >> 16;
  const float* W = (which == 0) ? Wk : ((which == 1) ? Wq : Wv);
  const int cc = c * 128 + ks * 32 + quad * 8 + j;
  const int h = nt * 16 + m;
  Wtf[tid] = __float2bfloat16(W[cc * 64 + h]);
}

// ---- kernel 1: qkv projection v3. 1024 blocks = one 16-row tile.
// XCD-PINNED (R-this): batch b runs only on XCD pair {2b,2b+1} via blockIdx%8,
// so Kf/Vf/qb for batch b are WRITTEN into the L2s that fa_pass1 will READ
// them from (fa_pass1 uses the same pinning).
// Phase 1: ALL threads stage the contiguous 64KB x-tile -> bf16 LDS (coalesced),
// ONE barrier. Phase 2: 4 waves x 3 output-tiles each (12 = K0-3,Q0-3,V0-3);
// 8 independent chunk-iters: 12 contiguous B-frag bursts from Wtf + 4 ds_read
// + 12 MFMA. No lockstep, max MLP. Stores: R3-verified frag-order swizzles.
__global__ __launch_bounds__(256) void proj_kernel(
    const float* __restrict__ x, const __hip_bfloat16* __restrict__ Wtf,
    __hip_bfloat16* __restrict__ qb, __hip_bfloat16* __restrict__ Kf,
    __hip_bfloat16* __restrict__ Vf) {
  __shared__ __hip_bfloat16 Xb[16 * XBS];
  const int tid = threadIdx.x;
  const int lane = tid & 63;
  const int wave = tid >> 6;
  const int m = lane & 15;
  const int quad = lane >> 4;
  // XCD-pinned tile assignment: 1024 blocks, 8 XCDs round-robin by blockIdx%8.
  const int bid = blockIdx.x;
  const int bb0 = (bid & 7) >> 1;                    // batch 0..3
  const int tile = ((bid >> 3) << 1) + (bid & 1);    // 0..255 within batch
  const int t0 = bb0 * T_ + tile * 16;

  // ---- phase 1: stage x-tile (contiguous 4096 float4), convert to bf16
  const float4* xtile = (const float4*)(x + (size_t)t0 * C_);
  float4 xv[16];
#pragma unroll
  for (int k = 0; k < 16; ++k) xv[k] = xtile[tid + k * 256];
#pragma unroll
  for (int k = 0; k < 16; ++k) {
    const int idx = tid + k * 256;
    const int row = idx >> 8;      // 256 float4 per row
    const int c4 = idx & 255;
    uint2 u = {pack2(xv[k].x, xv[k].y), pack2(xv[k].z, xv[k].w)};
    *(uint2*)(&Xb[row * XBS + c4 * 4]) = u;
  }
  __syncthreads();

  // ---- phase 2: wave owns output-tiles g = 3*wave .. 3*wave+2
  int whichs[3], ntls[3];
  const __hip_bfloat16* wb[3];
#pragma unroll
  for (int i = 0; i < 3; ++i) {
    const int g = wave * 3 + i;
    whichs[i] = g >> 2;
    ntls[i] = g & 3;
    wb[i] = Wtf + (size_t)whichs[i] * 65536 + ntls[i] * 512 + lane * 8;
  }
  f32x4 acc[3];
#pragma unroll
  for (int i = 0; i < 3; ++i) acc[i] = (f32x4){0.f, 0.f, 0.f, 0.f};

#pragma unroll
  for (int c = 0; c < 8; ++c) {
    bf16x8 bq[12];
#pragma unroll
    for (int i = 0; i < 3; ++i)
#pragma unroll
      for (int ks = 0; ks < 4; ++ks)
        bq[i * 4 + ks] = *(const bf16x8*)(wb[i] + (c * 16 + ks * 4) * 512);
#pragma unroll
    for (int ks = 0; ks < 4; ++ks) {
      bf16x8 a = *(const bf16x8*)(&Xb[m * XBS + c * 128 + ks * 32 + quad * 8]);
#pragma unroll
      for (int i = 0; i < 3; ++i)
        acc[i] = __builtin_amdgcn_mfma_f32_16x16x32_bf16(a, bq[i * 4 + ks],
                                                         acc[i], 0, 0, 0);
    }
  }

  // ---- stores
  const int bb = t0 >> 12;
  const int tloc = t0 & (T_ - 1);
  const int ktile = tloc >> 6;
  const float cscale = 0.18033688011112042f;  // log2(e)/sqrt(64)

#pragma unroll
  for (int i = 0; i < 3; ++i) {
    const int which = whichs[i];
    const int ntl = ntls[i];
    if (which == 1) {  // Q: row-major [t][h], PRE-SCALED into exp2 domain
#pragma unroll
      for (int r = 0; r < 4; ++r)
        qb[(size_t)(t0 + quad * 4 + r) * H_ + ntl * 16 + m] =
            __float2bfloat16(acc[i][r] * cscale);
    } else if (which == 0) {  // K -> frag order (R3-verified swizzle)
      __hip_bfloat16* dst = Kf + ((size_t)bb * 64 + ktile) * 4096;
      const int ntK = (tloc >> 4) & 3;
      const int wh = ntl >> 1;
      const int quadK = (ntl * 2 + (m >> 3)) & 3;
      const int j = m & 7;
#pragma unroll
      for (int r = 0; r < 4; ++r) {
        const int mK = quad * 4 + r;
        dst[(ntK * 2 + wh) * 512 + (quadK * 16 + mK) * 8 + j] =
            __float2bfloat16(acc[i][r]);
      }
    } else {  // V -> frag order (R3-verified swizzle)
      __hip_bfloat16* dst = Vf + ((size_t)bb * 64 + ktile) * 4096;
#pragma unroll
      for (int r = 0; r < 4; ++r) {
        const int kvo = (tloc & 63) + quad * 4 + r;
        const int half = (kvo >> 5) & 1;
        const int quadV = (kvo >> 3) & 3;
        const int j = kvo & 7;
        dst[(ntl * 2 + half) * 512 + (quadV * 16 + m) * 8 + j] =
            __float2bfloat16(acc[i][r]);
      }
    }
  }
}

// ---- kernel 2: flash pass1, S^T formulation + static-max softmax (R8, verified).
// R-this: XCD-pinned batches. blockIdx%8 selects the XCD (round-robin dispatch
// heuristic); batch b = xcd>>1, so each XCD pair streams only ITS batch's
// K+V frags (2MB+2MB = 4MB -> L2-resident) instead of all 16.8MB through L3.
// Jobs processed big-first (j2 reversed) so the 4608-over-4096-slot tail round
// runs the SMALL jobs. Opart/Ml stored nontemporal to protect K/V residency.
// Output addressing keyed by ORIGINAL jid -> combine unchanged.
__global__ __launch_bounds__(256, 4) void fa_pass1(
    const __hip_bfloat16* __restrict__ qg, const __hip_bfloat16* __restrict__ Kf,
    const __hip_bfloat16* __restrict__ Vf, float* __restrict__ Opart,
    float* __restrict__ Ml) {
  __shared__ __hip_bfloat16 Pl[4][16 * LSTR];  // P[q=16][kv=64] per wave
  const int lane = threadIdx.x & 63;
  const int wave = threadIdx.x >> 6;
  const int m = lane & 15;
  const int quad = lane >> 4;

  const int bid = blockIdx.x;                 // 0..1151
  const int xcd = bid & 7;
  const int b = xcd >> 1;                     // batch pinned to XCD pair
  const int pb = ((bid >> 3) << 1) + (xcd & 1);  // 0..287 per-batch block
  const int j2 = 1151 - (pb * 4 + wave);      // reversed: g=7 (8-tile) jobs first
  const int jid = b * 1152 + j2;              // ORIGINAL jid for output addressing
  int g = 7;
  while (16 * g * (g + 1) > j2) --g;          // qtile group: nc = g+1 chunks
  const int r2 = j2 - 16 * g * (g + 1);
  const int qt = 32 * g + r2 / (g + 1);
  const int c = r2 - (r2 / (g + 1)) * (g + 1);
  const int q0 = qt * 16;
  const int k0s = c * 512;
  const int kend0 = k0s + 512;
  const int kend = (kend0 < q0 + 16) ? kend0 : (q0 + 16);
  const int ntile = (kend - k0s + 63) >> 6;

  const __hip_bfloat16* qbase = qg + ((size_t)b * T_ + q0 + m) * H_;
  bf16x8 qf0 = *(const bf16x8*)(qbase + quad * 8);
  bf16x8 qf1 = *(const bf16x8*)(qbase + 32 + quad * 8);

  f32x4 Oacc[4];
#pragma unroll
  for (int i = 0; i < 4; ++i) Oacc[i] = (f32x4){0.f, 0.f, 0.f, 0.f};
  float psum = 0.f;

  const __hip_bfloat16* kgf = Kf + (size_t)b * 262144 + lane * 8;
  const __hip_bfloat16* vgf = Vf + (size_t)b * 262144 + lane * 8;
  __hip_bfloat16* Plw = &Pl[wave][0];

  for (int it = 0; it < ntile; ++it) {
    const int ktile = (k0s >> 6) + it;
    const int k0 = ktile * 64;
    const __hip_bfloat16* kp = kgf + (size_t)ktile * 4096;
    const __hip_bfloat16* vp = vgf + (size_t)ktile * 4096;

    f32x4 s[4];
#pragma unroll
    for (int nt = 0; nt < 4; ++nt) {
      bf16x8 kf0 = *(const bf16x8*)(kp + nt * 1024);
      bf16x8 kf1 = *(const bf16x8*)(kp + nt * 1024 + 512);
      f32x4 t = (f32x4){0.f, 0.f, 0.f, 0.f};
      t = __builtin_amdgcn_mfma_f32_16x16x32_bf16(kf0, qf0, t, 0, 0, 0);
      t = __builtin_amdgcn_mfma_f32_16x16x32_bf16(kf1, qf1, t, 0, 0, 0);
      s[nt] = t;
    }
    bf16x8 vf[8];
#pragma unroll
    for (int nt = 0; nt < 4; ++nt) {
      vf[2 * nt] = *(const bf16x8*)(vp + nt * 1024);
      vf[2 * nt + 1] = *(const bf16x8*)(vp + nt * 1024 + 512);
    }

    const bool needmask = (k0 + 63 > q0);
#pragma unroll
    for (int nt = 0; nt < 4; ++nt) {
      float p[4];
#pragma unroll
      for (int r = 0; r < 4; ++r) {
        float sv = s[nt][r];
        if (needmask && (k0 + nt * 16 + quad * 4 + r) > (q0 + m))
          sv = -__builtin_inff();
        p[r] = exp2f(sv);
        psum += p[r];
      }
      uint2 u = {pack2(p[0], p[1]), pack2(p[2], p[3])};
      *(uint2*)(&Plw[m * LSTR + nt * 16 + quad * 4]) = u;
    }

    bf16x8 pf0 = *(const bf16x8*)(&Plw[m * LSTR + quad * 8]);
    bf16x8 pf1 = *(const bf16x8*)(&Plw[m * LSTR + 32 + quad * 8]);
#pragma unroll
    for (int nt = 0; nt < 4; ++nt) {
      Oacc[nt] = __builtin_amdgcn_mfma_f32_16x16x32_bf16(pf0, vf[2 * nt], Oacc[nt], 0, 0, 0);
      Oacc[nt] = __builtin_amdgcn_mfma_f32_16x16x32_bf16(pf1, vf[2 * nt + 1], Oacc[nt], 0, 0, 0);
    }
  }

  psum += __shfl_xor(psum, 16);
  psum += __shfl_xor(psum, 32);

  // nontemporal: Opart/Ml stream 19MB; keep them out of the pinned K/V L2.
  float* Op = Opart + (size_t)jid * 1024;
#pragma unroll
  for (int nt = 0; nt < 4; ++nt)
#pragma unroll
    for (int r = 0; r < 4; ++r)
      __builtin_nontemporal_store(Oacc[nt][r],
                                  &Op[(quad * 4 + r) * 64 + nt * 16 + m]);
  if (lane < 16) __builtin_nontemporal_store(psum, &Ml[(size_t)jid * 16 + lane]);
}

// ---- kernel 3: combine partials — plain sums (static-max softmax).
__global__ __launch_bounds__(256) void fa_combine(
    const float* __restrict__ Opart, const float* __restrict__ Ml,
    float* __restrict__ out) {
  const int bq = blockIdx.x;
  const int b = bq >> 8;
  const int qt = bq & 255;
  const int g = qt >> 5;
  const int nc = g + 1;
  const int jbase = b * 1152 + 16 * g * (g + 1) + (qt & 31) * nc;
  const int r = threadIdx.x >> 4;
  const int h0 = (threadIdx.x & 15) * 4;

  float4 O = {0.f, 0.f, 0.f, 0.f};
  float L = 0.f;
  for (int c = 0; c < nc; ++c) {
    L += Ml[(size_t)(jbase + c) * 16 + r];
    float4 o = *(const float4*)(Opart + (size_t)(jbase + c) * 1024 + r * 64 + h0);
    O.x += o.x; O.y += o.y; O.z += o.z; O.w += o.w;
  }
  float inv = 1.f / L;
  float4 res = {O.x * inv, O.y * inv, O.z * inv, O.w * inv};
  *(float4*)(out + ((size_t)b * T_ + qt * 16 + r) * H_ + h0) = res;
}

extern "C" void kernel_launch(void* const* d_in, const int* in_sizes, int n_in,
                              void* d_out, int out_size, void* d_ws, size_t ws_size,
                              hipStream_t stream) {
  const float* x = (const float*)d_in[0];
  const float* Wk = (const float*)d_in[1];
  const float* Wq = (const float*)d_in[2];
  const float* Wv = (const float*)d_in[3];
  float* out = (float*)d_out;
  char* ws = (char*)d_ws;
  // ws: Wtf[192*1024]bf16(frag order) | qb[4][4096][64]bf16 | Kf[4][64][4096]bf16
  //     | Vf same | Opart[4608][16][64]f32 | Ml[4608][16]f32
  __hip_bfloat16* Wtf = (__hip_bfloat16*)ws;
  __hip_bfloat16* qb = (__hip_bfloat16*)(ws + 393216);
  __hip_bfloat16* Kf = (__hip_bfloat16*)(ws + 2490368);
  __hip_bfloat16* Vf = (__hip_bfloat16*)(ws + 4587520);
  float* Opart = (float*)(ws + 6684672);
  float* Ml = (float*)(ws + 25559040);

  hipLaunchKernelGGL(wtrans_kernel, dim3(768), dim3(256), 0, stream, Wk, Wq, Wv, Wtf);
  hipLaunchKernelGGL(proj_kernel, dim3(1024), dim3(256), 0, stream, x, Wtf, qb, Kf, Vf);
  hipLaunchKernelGGL(fa_pass1, dim3(1152), dim3(256), 0, stream, qb, Kf, Vf, Opart, Ml);
  hipLaunchKernelGGL(fa_combine, dim3(1024), dim3(256), 0, stream, Opart, Ml, out);
}